// Round 6
// baseline (436.192 us; speedup 1.0000x reference)
//
#include <hip/hip_runtime.h>
#include <cstddef>

#define Bn 128
#define Pn 8732
#define Cn 21
#define On 16
#define NW 32   // stream waves per image (each does up to 5 chunks of 64 priors)
#define NI 35   // ceil(Pn / 256) strided passes in the 256-thread reduce

__device__ __forceinline__ void argmax_combine(float& v, int& p, float v2, int p2) {
  if (v2 > v || (v2 == v && p2 < p)) { v = v2; p = p2; }
}

// LDS: stream staging and reduce scratch are lifetime-disjoint (barrier after
// the stream phase) -> union keeps the block at ~23 KB (6 blocks/CU cap).
union SmemU {
  struct {
    float4 row4[4][336];          // per-wave conf staging (21.5 KB)
    float  tt[4][On * 5];
    float  ar[4][On];
  } st;
  struct {
    unsigned hist[256 * 4];       // [bin][wave] -- 4 waves
    unsigned col[256];
    unsigned cand[64];
    float    t[On * 5];
    int      bp[On];
    float    redf[2][4];
    int      redi[4];
    unsigned prefix;
    int      kk, cnt, cc, np, fin;
  } rd;
};

// ---------------------------------------------------------------------------
// 256-thread per-image reduce (port of the 1024-thread kernel): forced
// matches, losses, exact top-k threshold via early-exit radix, counter-based
// global finalize (no spin-waits).
// ---------------------------------------------------------------------------
__device__ void reduce_image(
    int b, SmemU& u,
    const float* __restrict__ loc, const float* __restrict__ conf,
    const float* __restrict__ dbox, const float* __restrict__ targets,
    const float* __restrict__ ce0, const unsigned char* __restrict__ pack,
    const unsigned long long* __restrict__ keys,
    unsigned* res, unsigned* done2, float* out) {
  const int tid = threadIdx.x;
  const int wave = tid >> 6, lane = tid & 63;

  __threadfence();   // acquire: other XCDs' ce0/pack/keys writes (flag seen)

  if (tid < On * 5) u.rd.t[tid] = targets[(size_t)b * On * 5 + tid];
  if (tid < On)
    u.rd.bp[tid] = (int)(0xFFFFFFFFu - (unsigned)(keys[b * On + tid] & 0xFFFFFFFFull));
  __syncthreads();

  float ce_r[NI];                  // straight-line unconditional -> registers
  float my_loc = 0.0f, my_cep = 0.0f; int my_np = 0;
  #pragma unroll
  for (int sI = 0; sI < NI; sI++) {
    ce_r[sI] = 0.0f;
    const int p = tid + 256 * sI;
    if (p < Pn) {
      unsigned char pk = pack[(size_t)b * Pn + p];
      float c0 = ce0[(size_t)b * Pn + p];
      int pos = pk >> 4;
      int bt = pk & 15;
      #pragma unroll
      for (int j = 0; j < On; j++)
        if (u.rd.bp[j] == p) { bt = j; pos = 1; }   // ascending: last j wins
      ce_r[sI] = pos ? 0.0f : c0;
      if (pos) {
        my_np++;
        const float* t = &u.rd.t[bt * 5];
        int c = (int)t[4] + 1;
        const float* row = conf + ((size_t)b * Pn + p) * Cn;
        my_cep += c0 + row[0] - row[c];             // lse - x[c]
        float4 d = ((const float4*)dbox)[p];
        float mx1 = t[0], my1 = t[1], mx2 = t[2], my2 = t[3];
        float g0 = ((mx1 + mx2) * 0.5f - d.x) / (0.1f * d.z);
        float g1 = ((my1 + my2) * 0.5f - d.y) / (0.1f * d.w);
        float g2 = logf((mx2 - mx1) / d.z) / 0.2f;
        float g3 = logf((my2 - my1) / d.w) / 0.2f;
        float4 ld = ((const float4*)loc)[(size_t)b * Pn + p];
        float g[4] = {g0, g1, g2, g3};
        float l[4] = {ld.x, ld.y, ld.z, ld.w};
        #pragma unroll
        for (int q = 0; q < 4; q++) {
          float ad = fabsf(l[q] - g[q]);
          my_loc += (ad < 1.0f) ? 0.5f * ad * ad : ad - 0.5f;
        }
      }
    }
  }

  {
    int np = my_np;
    #pragma unroll
    for (int off = 32; off; off >>= 1) np += __shfl_down(np, off);
    if (lane == 0) u.rd.redi[wave] = np;
  }
  __syncthreads();
  if (tid == 0)
    u.rd.np = u.rd.redi[0] + u.rd.redi[1] + u.rd.redi[2] + u.rd.redi[3];
  __syncthreads();

  // ---- exact k-th largest over ce_r (all >= 0) ----
  const int k = min(u.rd.np * 3, Pn);
  unsigned prefix = 0, maskb = 0;
  int kk = k;
  int cntc = Pn;
  for (int shift = 24; shift >= 0; shift -= 8) {
    if (cntc <= 64) break;                         // small-select path below
    ((uint4*)u.rd.hist)[tid] = make_uint4(0u, 0u, 0u, 0u);
    __syncthreads();
    #pragma unroll
    for (int sI = 0; sI < NI; sI++) {
      const int p = tid + 256 * sI;
      if (p < Pn) {
        unsigned uu = __float_as_uint(ce_r[sI]);
        if ((uu & maskb) == prefix)
          atomicAdd(&u.rd.hist[(((uu >> shift) & 255u) << 2) + (unsigned)wave], 1u);
      }
    }
    __syncthreads();
    {
      unsigned c = u.rd.hist[tid * 4 + 0] + u.rd.hist[tid * 4 + 1] +
                   u.rd.hist[tid * 4 + 2] + u.rd.hist[tid * 4 + 3];
      u.rd.col[tid] = c;
    }
    __syncthreads();
    if (tid < 64) {
      // wave-0 parallel suffix scan over 256 bins (4 per lane)
      unsigned c0 = u.rd.col[4 * tid + 0], c1 = u.rd.col[4 * tid + 1];
      unsigned c2 = u.rd.col[4 * tid + 2], c3 = u.rd.col[4 * tid + 3];
      unsigned t0 = c0 + c1 + c2 + c3;
      unsigned S = t0;
      #pragma unroll
      for (int off = 1; off < 64; off <<= 1) {
        unsigned o = __shfl_down(S, off);
        if (tid + off < 64) S += o;
      }
      unsigned Snext = S - t0;                     // suffix of lanes > tid
      unsigned s3 = Snext + c3;
      unsigned s2 = s3 + c2;
      unsigned s1 = s2 + c1;
      unsigned s0 = s1 + c0;
      unsigned kk_u = (unsigned)kk;
      int chosen = -1; unsigned snx = 0, cc = 0;
      if (s3 >= kk_u && Snext < kk_u)      { chosen = 3; snx = Snext; cc = c3; }
      else if (s2 >= kk_u && s3 < kk_u)    { chosen = 2; snx = s3;    cc = c2; }
      else if (s1 >= kk_u && s2 < kk_u)    { chosen = 1; snx = s2;    cc = c1; }
      else if (s0 >= kk_u && s1 < kk_u)    { chosen = 0; snx = s1;    cc = c0; }
      if (chosen >= 0) {                           // exactly one lane hits
        u.rd.prefix = prefix | ((unsigned)(4 * tid + chosen) << shift);
        u.rd.kk = (int)(kk_u - snx);
        u.rd.cnt = (int)cc;
      }
    }
    __syncthreads();
    prefix = u.rd.prefix; kk = u.rd.kk; cntc = u.rd.cnt;
    maskb |= 255u << shift;
  }
  if (maskb != 0xFFFFFFFFu) {
    // <= 64 candidates share the prefix: exact rank-select in one wave
    if (tid == 0) u.rd.cc = 0;
    __syncthreads();
    #pragma unroll
    for (int sI = 0; sI < NI; sI++) {
      const int p = tid + 256 * sI;
      if (p < Pn) {
        unsigned uu = __float_as_uint(ce_r[sI]);
        if ((uu & maskb) == prefix) {
          int ix = atomicAdd(&u.rd.cc, 1);
          u.rd.cand[ix] = uu;
        }
      }
    }
    __syncthreads();
    if (tid < 64) {
      int c = u.rd.cc;
      if (tid < c) {
        unsigned v = u.rd.cand[tid];
        int g = 0, e = 0;
        for (int i = 0; i < c; i++) {
          unsigned w = u.rd.cand[i];
          g += (w > v); e += (w == v);
        }
        if (g < kk && kk <= g + e) u.rd.prefix = v; // tie-safe: writers equal
      }
    }
    __syncthreads();
    prefix = u.rd.prefix;
  }
  float T = __uint_as_float(prefix);

  float sum_gt = 0.0f; int cnt_gt = 0;
  #pragma unroll
  for (int sI = 0; sI < NI; sI++) {
    const int p = tid + 256 * sI;
    if (p < Pn) {
      float x = ce_r[sI];
      if (x > T) { sum_gt += x; cnt_gt++; }
    }
  }
  #pragma unroll
  for (int off = 32; off; off >>= 1) {
    sum_gt += __shfl_down(sum_gt, off);
    cnt_gt += __shfl_down(cnt_gt, off);
    my_loc += __shfl_down(my_loc, off);
    my_cep += __shfl_down(my_cep, off);
  }
  if (lane == 0) {
    u.rd.redf[0][wave] = my_loc;
    u.rd.redf[1][wave] = sum_gt + my_cep;
    u.rd.redi[wave] = cnt_gt;
  }
  __syncthreads();
  if (tid == 0) {
    float ll = 0.0f, lc = 0.0f; int cg2 = 0;
    #pragma unroll
    for (int w = 0; w < 4; w++) {
      ll += u.rd.redf[0][w]; lc += u.rd.redf[1][w]; cg2 += u.rd.redi[w];
    }
    lc += (k > 0) ? (float)(k - cg2) * T : 0.0f;
    atomicExch(&res[b * 4 + 0], __float_as_uint(ll));
    atomicExch(&res[b * 4 + 1], __float_as_uint(lc));
    atomicExch(&res[b * 4 + 2], (unsigned)u.rd.np);
    __threadfence();                               // release partials
    unsigned o2 = atomicAdd(done2, 1u);
    u.rd.fin = (o2 == (unsigned)(Bn - 1)) ? 1 : 0; // last reduce finalizes
  }
  __syncthreads();
  if (u.rd.fin) {
    __threadfence();                               // acquire all partials
    float ll = 0.0f, lc = 0.0f; int np = 0;
    if (tid < Bn) {
      ll = __uint_as_float(atomicAdd(&res[tid * 4 + 0], 0u));
      lc = __uint_as_float(atomicAdd(&res[tid * 4 + 1], 0u));
      np = (int)atomicAdd(&res[tid * 4 + 2], 0u);
    }
    #pragma unroll
    for (int off = 32; off; off >>= 1) {
      ll += __shfl_down(ll, off);
      lc += __shfl_down(lc, off);
      np += __shfl_down(np, off);
    }
    if (lane == 0 && wave < 2) {
      u.rd.redf[0][wave] = ll; u.rd.redf[1][wave] = lc; u.rd.redi[wave] = np;
    }
    __syncthreads();
    if (tid == 0) {
      float L = u.rd.redf[0][0] + u.rd.redf[0][1];
      float C = u.rd.redf[1][0] + u.rd.redf[1][1];
      float N = (float)(u.rd.redi[0] + u.rd.redi[1]);
      out[0] = L / N;
      out[1] = C / N;
    }
  }
  __syncthreads();   // protect rd.* before a possible next reduce in this block
}

// ---------------------------------------------------------------------------
// Fused kernel: stream phase (round-2 structure, 62us: coalesced LDS staging,
// 5 chunks/wave, barrier-free per-wave buffers) + per-image counter-gated
// reduce + counter-gated global finalize. One launch, no spin-waits.
// ---------------------------------------------------------------------------
__global__ __launch_bounds__(256) void fused_kernel(
    const float* __restrict__ loc, const float* __restrict__ conf,
    const float* __restrict__ dbox, const float* __restrict__ targets,
    float* __restrict__ ce0, unsigned char* __restrict__ pack,
    unsigned long long* __restrict__ keys,
    unsigned* __restrict__ res, float* __restrict__ out) {
  const int wb = threadIdx.x >> 6, lane = threadIdx.x & 63;
  const int wave_g = blockIdx.x * 4 + wb;
  const int b = wave_g & 127;
  const int cg = wave_g >> 7;                    // 0..31

  unsigned* done  = res + Bn * 4;                // [Bn] per-image wave counter
  unsigned* done2 = done + Bn;                   // [1] reduce-complete counter

  __shared__ SmemU u;
  __shared__ int s_job[4];

  // ---- targets staging (On*5=80 > 64 lanes: strided) ----
  #pragma unroll
  for (int i = lane; i < On * 5; i += 64)
    u.st.tt[wb][i] = targets[(size_t)b * On * 5 + i];
  if (lane < On) {
    float x1 = targets[(size_t)b * On * 5 + lane * 5 + 0];
    float y1 = targets[(size_t)b * On * 5 + lane * 5 + 1];
    float x2 = targets[(size_t)b * On * 5 + lane * 5 + 2];
    float y2 = targets[(size_t)b * On * 5 + lane * 5 + 3];
    u.st.ar[wb][lane] = (x2 - x1) * (y2 - y1);
  }

  float bestv[On]; int bestp[On];
  #pragma unroll
  for (int j = 0; j < On; j++) { bestv[j] = -1.0f; bestp[j] = 0x7fffffff; }

  #pragma unroll
  for (int i = 0; i < 5; i++) {
    const int ci = cg + 32 * i;
    if (ci >= 137) break;
    const int p0 = ci * 64;
    const int rows = min(64, Pn - p0);           // 64 or 28 (both %4==0)
    const int n4 = rows * Cn / 4;                // 336 or 147

    const float4* src = (const float4*)(conf + ((size_t)b * Pn + p0) * Cn);
    float4 v0, v1, v2, v3, v4, v5;
    if (lane < n4)        v0 = src[lane];
    if (lane + 64 < n4)   v1 = src[lane + 64];
    if (lane + 128 < n4)  v2 = src[lane + 128];
    if (lane + 192 < n4)  v3 = src[lane + 192];
    if (lane + 256 < n4)  v4 = src[lane + 256];
    if (lane + 320 < n4)  v5 = src[lane + 320];
    if (lane < n4)        u.st.row4[wb][lane] = v0;
    if (lane + 64 < n4)   u.st.row4[wb][lane + 64] = v1;
    if (lane + 128 < n4)  u.st.row4[wb][lane + 128] = v2;
    if (lane + 192 < n4)  u.st.row4[wb][lane + 192] = v3;
    if (lane + 256 < n4)  u.st.row4[wb][lane + 256] = v4;
    if (lane + 320 < n4)  u.st.row4[wb][lane + 320] = v5;

    if (lane < rows) {
      const int p = p0 + lane;
      const float* x = (const float*)u.st.row4[wb] + lane * Cn;
      float m = x[0];
      #pragma unroll
      for (int q = 1; q < Cn; q++) m = fmaxf(m, x[q]);
      float s = 0.0f;
      #pragma unroll
      for (int q = 0; q < Cn; q++) s += __expf(x[q] - m);
      float lse = m + __logf(s);
      ce0[(size_t)b * Pn + p] = lse - x[0];

      float4 d = ((const float4*)dbox)[p];
      float px1 = d.x - d.z * 0.5f, py1 = d.y - d.w * 0.5f;
      float px2 = d.x + d.z * 0.5f, py2 = d.y + d.w * 0.5f;
      float ap = d.z * d.w;
      float mv = -1.0f; int mj = 0;
      #pragma unroll
      for (int j = 0; j < On; j++) {
        float lx = fmaxf(u.st.tt[wb][j*5+0], px1);
        float ly = fmaxf(u.st.tt[wb][j*5+1], py1);
        float rx = fminf(u.st.tt[wb][j*5+2], px2);
        float ry = fminf(u.st.tt[wb][j*5+3], py2);
        float w = fmaxf(rx - lx, 0.0f), h = fmaxf(ry - ly, 0.0f);
        float inter = w * h;
        float ov = __fdividef(inter, u.st.ar[wb][j] + ap - inter);
        if (ov > bestv[j]) { bestv[j] = ov; bestp[j] = p; }  // smallest p kept
        if (ov > mv) { mv = ov; mj = j; }                    // first max over j
      }
      pack[(size_t)b * Pn + p] =
          (unsigned char)(mj | ((mv >= 0.5f) ? 16 : 0));
    }
  }

  // per-truth argmax: wave shuffle reduce, then device atomicMax
  #pragma unroll
  for (int j = 0; j < On; j++) {
    float v = bestv[j]; int p = bestp[j];
    #pragma unroll
    for (int off = 32; off; off >>= 1) {
      float v2 = __shfl_down(v, off);
      int p2 = __shfl_down(p, off);
      argmax_combine(v, p, v2, p2);
    }
    if (lane == 0) {
      unsigned long long key;
      if (v < 0.0f) key = 0xC000000000000000ull;   // neutral, still beats poison
      else key = (((unsigned long long)(__float_as_uint(v) | 0xC0000000u)) << 32)
               | (unsigned long long)(0xFFFFFFFFu - (unsigned)p);
      atomicMax(&keys[b * On + j], key);
    }
  }

  // ---- completion signal: last wave of image b claims the reduce job ----
  if (lane == 0) {
    __threadfence();                              // release ce0/pack stores
    unsigned old = atomicAdd(&done[b], 1u);
    s_job[wb] = (old == (unsigned)(NW - 1)) ? b : -1;
  }
  __syncthreads();                                // also fences union st->rd

  for (int s = 0; s < 4; ++s) {
    const int img = s_job[s];                     // block-uniform (LDS)
    if (img >= 0)
      reduce_image(img, u, loc, conf, dbox, targets, ce0, pack, keys,
                   res, done2, out);
  }
}

extern "C" void kernel_launch(void* const* d_in, const int* in_sizes, int n_in,
                              void* d_out, int out_size, void* d_ws, size_t ws_size,
                              hipStream_t stream) {
  const float* loc_data  = (const float*)d_in[0];
  const float* conf_data = (const float*)d_in[1];
  const float* dbox      = (const float*)d_in[2];
  const float* targets   = (const float*)d_in[3];
  float* out = (float*)d_out;

  char* ws = (char*)d_ws;
  float* ce0 = (float*)ws;                                           // B*P f32
  unsigned char* pack = (unsigned char*)(ws + (size_t)Bn * Pn * 4);  // B*P bytes
  unsigned long long* keys =
      (unsigned long long*)(ws + (size_t)Bn * Pn * 5);               // B*16 u64
  unsigned int* res =
      (unsigned int*)(ws + (size_t)Bn * Pn * 5 + Bn * On * 8);       // B*4 + B + 1 u32

  // zero res/done/done2 (keys relies on poison-beating key encoding)
  hipMemsetAsync(res, 0, (size_t)(Bn * 4 + Bn + 1) * sizeof(unsigned), stream);

  fused_kernel<<<Bn * NW / 4, 256, 0, stream>>>(
      loc_data, conf_data, dbox, targets, ce0, pack, keys, res, out);
}

// Round 8
// 210.298 us; speedup vs baseline: 2.0742x; 2.0742x over previous
//
#include <hip/hip_runtime.h>
#include <cstddef>

#define Bn 128
#define Pn 8732
#define Cn 21
#define On 16
#define MAGIC 0x13579BDFu

__device__ __forceinline__ void argmax_combine(float& v, int& p, float v2, int p2) {
  if (v2 > v || (v2 == v && p2 < p)) { v = v2; p = p2; }
}

// Smooth-L1 of (loc - encode(truth, dbox)). Shared by stream and reduce so the
// forced-match subtraction cancels stream's contribution bit-exactly.
__device__ __forceinline__ float sl1_enc(float4 lv, float4 d,
                                         float t0, float t1, float t2, float t3) {
  float g0 = ((t0 + t2) * 0.5f - d.x) / (0.1f * d.z);
  float g1 = ((t1 + t3) * 0.5f - d.y) / (0.1f * d.w);
  float g2 = __logf((t2 - t0) / d.z) / 0.2f;
  float g3 = __logf((t3 - t1) / d.w) / 0.2f;
  float r = 0.f, a;
  a = fabsf(lv.x - g0); r += (a < 1.f) ? 0.5f * a * a : a - 0.5f;
  a = fabsf(lv.y - g1); r += (a < 1.f) ? 0.5f * a * a : a - 0.5f;
  a = fabsf(lv.z - g2); r += (a < 1.f) ? 0.5f * a * a : a - 0.5f;
  a = fabsf(lv.w - g3); r += (a < 1.f) ? 0.5f * a * a : a - 0.5f;
  return r;
}

// ---------------------------------------------------------------------------
// Kernel A (round-2 structure + pos-work migration): streams conf (94 MB),
// computes softmax CE, IoU matching, AND the positive-prior losses:
// per-image {loc_loss, ce_pos, num_pos} accumulated via wave-reduce +
// 3 atomicAdds. ce0 = pos ? 0 : lse - x[0] (neg pool pre-zeroed at pos).
// pack byte (mj | pos<<4) kept: reduce reads it only for <=16 forced priors.
// ---------------------------------------------------------------------------
__global__ __launch_bounds__(256) void stream_kernel(
    const float* __restrict__ loc, const float* __restrict__ conf,
    const float* __restrict__ dbox, const float* __restrict__ targets,
    float* __restrict__ ce0, unsigned char* __restrict__ pack,
    unsigned long long* __restrict__ keys, unsigned* __restrict__ part) {
  const int wb = threadIdx.x >> 6, lane = threadIdx.x & 63;
  const int wave_g = blockIdx.x * 4 + wb;
  const int b = wave_g & 127;
  const int cg = wave_g >> 7;                    // 0..31

  __shared__ float4 s_row4[4][336];              // 5376 B per wave
  __shared__ float s_tt[4][On * 5];
  __shared__ float s_ar[4][On];

  // On*5 = 80 > 64 lanes: strided fill covers elements 64..79 (truths 12-15).
  for (int i = lane; i < On * 5; i += 64)
    s_tt[wb][i] = targets[(size_t)b * On * 5 + i];
  if (lane < On) {
    float x1 = targets[(size_t)b * On * 5 + lane * 5 + 0];
    float y1 = targets[(size_t)b * On * 5 + lane * 5 + 1];
    float x2 = targets[(size_t)b * On * 5 + lane * 5 + 2];
    float y2 = targets[(size_t)b * On * 5 + lane * 5 + 3];
    s_ar[wb][lane] = (x2 - x1) * (y2 - y1);
  }

  float bestv[On]; int bestp[On];
  #pragma unroll
  for (int j = 0; j < On; j++) { bestv[j] = -1.0f; bestp[j] = 0x7fffffff; }

  float acc_loc = 0.0f, acc_cep = 0.0f; int acc_np = 0;

  #pragma unroll
  for (int i = 0; i < 5; i++) {
    const int ci = cg + 32 * i;
    if (ci >= 137) break;
    const int p0 = ci * 64;
    const int rows = min(64, Pn - p0);           // 64 or 28 (both %4==0)
    const int n4 = rows * Cn / 4;                // 336 or 147

    const float4* src = (const float4*)(conf + ((size_t)b * Pn + p0) * Cn);
    float4 v0, v1, v2, v3, v4, v5;
    if (lane < n4)        v0 = src[lane];
    if (lane + 64 < n4)   v1 = src[lane + 64];
    if (lane + 128 < n4)  v2 = src[lane + 128];
    if (lane + 192 < n4)  v3 = src[lane + 192];
    if (lane + 256 < n4)  v4 = src[lane + 256];
    if (lane + 320 < n4)  v5 = src[lane + 320];
    if (lane < n4)        s_row4[wb][lane] = v0;
    if (lane + 64 < n4)   s_row4[wb][lane + 64] = v1;
    if (lane + 128 < n4)  s_row4[wb][lane + 128] = v2;
    if (lane + 192 < n4)  s_row4[wb][lane + 192] = v3;
    if (lane + 256 < n4)  s_row4[wb][lane + 256] = v4;
    if (lane + 320 < n4)  s_row4[wb][lane + 320] = v5;

    if (lane < rows) {
      const int p = p0 + lane;
      const float* x = (const float*)s_row4[wb] + lane * Cn;  // stride 21: 2-way, free
      float m = x[0];
      #pragma unroll
      for (int q = 1; q < Cn; q++) m = fmaxf(m, x[q]);
      float s = 0.0f;
      #pragma unroll
      for (int q = 0; q < Cn; q++) s += __expf(x[q] - m);
      float lse = m + __logf(s);

      float4 d = ((const float4*)dbox)[p];
      float px1 = d.x - d.z * 0.5f, py1 = d.y - d.w * 0.5f;
      float px2 = d.x + d.z * 0.5f, py2 = d.y + d.w * 0.5f;
      float ap = d.z * d.w;
      float mv = -1.0f; int mj = 0;
      #pragma unroll
      for (int j = 0; j < On; j++) {
        float lx = fmaxf(s_tt[wb][j*5+0], px1);
        float ly = fmaxf(s_tt[wb][j*5+1], py1);
        float rx = fminf(s_tt[wb][j*5+2], px2);
        float ry = fminf(s_tt[wb][j*5+3], py2);
        float w = fmaxf(rx - lx, 0.0f), h = fmaxf(ry - ly, 0.0f);
        float inter = w * h;
        float ov = __fdividef(inter, s_ar[wb][j] + ap - inter);
        if (ov > bestv[j]) { bestv[j] = ov; bestp[j] = p; }  // smallest p kept
        if (ov > mv) { mv = ov; mj = j; }                    // first max over j
      }
      const bool pos = (mv >= 0.5f);
      pack[(size_t)b * Pn + p] = (unsigned char)(mj | (pos ? 16 : 0));
      ce0[(size_t)b * Pn + p] = pos ? 0.0f : (lse - x[0]);

      if (pos) {
        acc_np++;
        int c = (int)s_tt[wb][mj * 5 + 4] + 1;
        acc_cep += lse - x[c];
        float4 lv = ((const float4*)loc)[(size_t)b * Pn + p];
        acc_loc += sl1_enc(lv, d, s_tt[wb][mj*5+0], s_tt[wb][mj*5+1],
                                  s_tt[wb][mj*5+2], s_tt[wb][mj*5+3]);
      }
    }
  }

  // per-image partial sums: one wave-reduce + 3 atomics per wave
  #pragma unroll
  for (int off = 32; off; off >>= 1) {
    acc_loc += __shfl_down(acc_loc, off);
    acc_cep += __shfl_down(acc_cep, off);
    acc_np  += __shfl_down(acc_np, off);
  }
  if (lane == 0) {
    atomicAdd((float*)&part[b * 4 + 0], acc_loc);
    atomicAdd((float*)&part[b * 4 + 1], acc_cep);
    atomicAdd(&part[b * 4 + 2], (unsigned)acc_np);
  }

  // per-truth argmax: wave shuffle reduce, then device atomicMax
  #pragma unroll
  for (int j = 0; j < On; j++) {
    float v = bestv[j]; int p = bestp[j];
    #pragma unroll
    for (int off = 32; off; off >>= 1) {
      float v2 = __shfl_down(v, off);
      int p2 = __shfl_down(p, off);
      argmax_combine(v, p, v2, p2);
    }
    if (lane == 0) {
      unsigned long long key;
      if (v < 0.0f) key = 0xC000000000000000ull;   // neutral, still beats poison
      else key = (((unsigned long long)(__float_as_uint(v) | 0xC0000000u)) << 32)
               | (unsigned long long)(0xFFFFFFFFu - (unsigned)p);
      atomicMax(&keys[b * On + j], key);
    }
  }
}

// ---------------------------------------------------------------------------
// Kernel B: per-image (128 blocks x 1024). Forced-match corrections (<=16
// priors: subtract stream's old-truth terms, add new-truth terms), then a
// light data pass (ce0 only, float4), exact top-k radix, MAGIC finalize.
// ---------------------------------------------------------------------------
__global__ __launch_bounds__(1024) void reduce_kernel(
    const float* __restrict__ loc, const float* __restrict__ conf,
    const float* __restrict__ dbox, const float* __restrict__ targets,
    const float* __restrict__ ce0, const unsigned char* __restrict__ pack,
    const unsigned long long* __restrict__ keys,
    const unsigned* __restrict__ part,
    unsigned int* __restrict__ res, float* __restrict__ out) {
  const int b = blockIdx.x;
  const int tid = threadIdx.x;
  const int wave = tid >> 6, lane = tid & 63;

  __shared__ float s_t[On * 5];
  __shared__ int s_bp[On];
  __shared__ unsigned s_pk[On];
  __shared__ int s_fp[On];
  __shared__ unsigned hist[256 * 16];       // [bin][wave], 16 KB
  __shared__ unsigned s_col[256];
  __shared__ unsigned s_cand[64];
  __shared__ float s_redf[16];
  __shared__ int s_redi[16];
  __shared__ unsigned s_prefix;
  __shared__ int s_kk;
  __shared__ int s_cnt;
  __shared__ int s_cc2;
  __shared__ int s_cc;                      // forced-exclusion count
  __shared__ int s_np;
  __shared__ float s_ltot, s_ctot;

  if (tid < On * 5) s_t[tid] = targets[(size_t)b * On * 5 + tid];
  if (tid < On) {
    int bp = (int)(0xFFFFFFFFu - (unsigned)(keys[b * On + tid] & 0xFFFFFFFFull));
    s_bp[tid] = bp;
    s_pk[tid] = pack[(size_t)b * Pn + bp];
  }
  if (tid == 1023) s_cc = 0;
  __syncthreads();

  // ---- forced-match corrections: wave 0, lane j handles truth j ----
  if (wave == 0) {
    const bool valid = lane < On;
    const int p = valid ? s_bp[lane] : 0;
    bool dup = false;
    if (valid)
      for (int j2 = lane + 1; j2 < On; j2++) dup |= (s_bp[j2] == p);
    const bool act = valid && !dup;          // last j wins on collisions
    float dloc = 0.f, dcep = 0.f; int dnp = 0;
    if (act) {
      const unsigned pk = s_pk[lane];
      const int pos0 = pk >> 4, mjo = pk & 15;
      const float* row = conf + ((size_t)b * Pn + p) * Cn;
      float xr[Cn];
      #pragma unroll
      for (int q = 0; q < Cn; q++) xr[q] = row[q];
      float m = xr[0];
      #pragma unroll
      for (int q = 1; q < Cn; q++) m = fmaxf(m, xr[q]);
      float s = 0.f;
      #pragma unroll
      for (int q = 0; q < Cn; q++) s += __expf(xr[q] - m);
      const float lse = m + __logf(s);
      const float4 d = ((const float4*)dbox)[p];
      const float4 lv = ((const float4*)loc)[(size_t)b * Pn + p];
      const int cn = (int)s_t[lane * 5 + 4] + 1;       // new class (truth=lane)
      dcep = lse - xr[cn];
      dloc = sl1_enc(lv, d, s_t[lane*5+0], s_t[lane*5+1],
                            s_t[lane*5+2], s_t[lane*5+3]);
      if (pos0) {
        const int co = (int)s_t[mjo * 5 + 4] + 1;      // cancel stream's terms
        dcep -= lse - xr[co];
        dloc -= sl1_enc(lv, d, s_t[mjo*5+0], s_t[mjo*5+1],
                              s_t[mjo*5+2], s_t[mjo*5+3]);
      } else {
        dnp = 1;
        int ix = atomicAdd(&s_cc, 1);
        if (ix < On) s_fp[ix] = p;                     // exclude from neg pool
      }
    }
    #pragma unroll
    for (int off = 32; off; off >>= 1) {
      dloc += __shfl_down(dloc, off);
      dcep += __shfl_down(dcep, off);
      dnp  += __shfl_down(dnp, off);
    }
    if (lane == 0) {
      s_ltot = __uint_as_float(part[b * 4 + 0]) + dloc;
      s_ctot = __uint_as_float(part[b * 4 + 1]) + dcep;
      s_np = (int)part[b * 4 + 2] + dnp;
    }
  }
  __syncthreads();

  // ---- data pass: ce0 only, float4 (Pn = 4*2183 exactly) ----
  const int ncnt = s_cc;
  float ce_r[12];
  #pragma unroll
  for (int sI = 0; sI < 3; sI++) {
    const int f = tid + 1024 * sI;
    float4 v = make_float4(0.f, 0.f, 0.f, 0.f);
    if (f < Pn / 4) v = ((const float4*)ce0)[(size_t)b * (Pn / 4) + f];
    ce_r[4*sI+0] = v.x; ce_r[4*sI+1] = v.y; ce_r[4*sI+2] = v.z; ce_r[4*sI+3] = v.w;
  }
  for (int i = 0; i < ncnt; i++) {
    const int fp = s_fp[i];
    #pragma unroll
    for (int sI = 0; sI < 3; sI++) {
      const int f = tid + 1024 * sI;
      #pragma unroll
      for (int q = 0; q < 4; q++)
        if (4 * f + q == fp) ce_r[4*sI+q] = 0.f;       // newly-pos: not neg
    }
  }

  // ---- exact k-th largest over ce_r (all >= 0; padding zeros harmless) ----
  const int k = min(s_np * 3, Pn);
  unsigned prefix = 0, maskb = 0;
  int kk = k;
  int cntc = 12288;
  for (int shift = 24; shift >= 0; shift -= 8) {
    if (cntc <= 64) break;                         // small-select path below
    ((uint4*)hist)[tid] = make_uint4(0u, 0u, 0u, 0u);
    __syncthreads();
    #pragma unroll
    for (int r = 0; r < 12; r++) {
      unsigned u = __float_as_uint(ce_r[r]);
      if ((u & maskb) == prefix)
        atomicAdd(&hist[(((u >> shift) & 255u) << 4) + (unsigned)wave], 1u);
    }
    __syncthreads();
    if (tid < 256) {
      unsigned c = 0;
      #pragma unroll
      for (int w = 0; w < 16; w++) c += hist[(tid << 4) + w];
      s_col[tid] = c;
    }
    __syncthreads();
    if (tid < 64) {
      // wave-0 parallel suffix scan over 256 bins (4 per lane)
      unsigned c0 = s_col[4 * tid + 0], c1 = s_col[4 * tid + 1];
      unsigned c2 = s_col[4 * tid + 2], c3 = s_col[4 * tid + 3];
      unsigned t0 = c0 + c1 + c2 + c3;
      unsigned S = t0;
      #pragma unroll
      for (int off = 1; off < 64; off <<= 1) {
        unsigned o = __shfl_down(S, off);
        if (tid + off < 64) S += o;
      }
      unsigned Snext = S - t0;                     // suffix of lanes > tid
      unsigned s3 = Snext + c3;
      unsigned s2 = s3 + c2;
      unsigned s1 = s2 + c1;
      unsigned s0 = s1 + c0;
      unsigned kk_u = (unsigned)kk;
      int chosen = -1; unsigned snx = 0, cc = 0;
      if (s3 >= kk_u && Snext < kk_u)      { chosen = 3; snx = Snext; cc = c3; }
      else if (s2 >= kk_u && s3 < kk_u)    { chosen = 2; snx = s3;    cc = c2; }
      else if (s1 >= kk_u && s2 < kk_u)    { chosen = 1; snx = s2;    cc = c1; }
      else if (s0 >= kk_u && s1 < kk_u)    { chosen = 0; snx = s1;    cc = c0; }
      if (chosen >= 0) {                           // exactly one lane hits
        s_prefix = prefix | ((unsigned)(4 * tid + chosen) << shift);
        s_kk = (int)(kk_u - snx);
        s_cnt = (int)cc;
      }
    }
    __syncthreads();
    prefix = s_prefix; kk = s_kk; cntc = s_cnt;
    maskb |= 255u << shift;
  }
  if (maskb != 0xFFFFFFFFu) {
    // <= 64 candidates share the prefix: exact rank-select in one wave
    if (tid == 0) s_cc2 = 0;
    __syncthreads();
    #pragma unroll
    for (int r = 0; r < 12; r++) {
      unsigned u = __float_as_uint(ce_r[r]);
      if ((u & maskb) == prefix) {
        int ix = atomicAdd(&s_cc2, 1);
        if (ix < 64) s_cand[ix] = u;
      }
    }
    __syncthreads();
    if (tid < 64) {
      int c = min(s_cc2, 64);
      if (tid < c) {
        unsigned v = s_cand[tid];
        int g = 0, e = 0;
        for (int i = 0; i < c; i++) {
          unsigned w = s_cand[i];
          g += (w > v); e += (w == v);
        }
        if (g < kk && kk <= g + e) s_prefix = v;   // tie-safe: all writers equal
      }
    }
    __syncthreads();
    prefix = s_prefix;
  }
  float T = __uint_as_float(prefix);

  float sum_gt = 0.0f; int cnt_gt = 0;
  #pragma unroll
  for (int r = 0; r < 12; r++) {
    float x = ce_r[r];
    if (x > T) { sum_gt += x; cnt_gt++; }
  }
  #pragma unroll
  for (int off = 32; off; off >>= 1) {
    sum_gt += __shfl_down(sum_gt, off);
    cnt_gt += __shfl_down(cnt_gt, off);
  }
  if (lane == 0) { s_redf[wave] = sum_gt; s_redi[wave] = cnt_gt; }
  __syncthreads();
  if (tid == 0) {
    float sg = 0.0f; int cg2 = 0;
    #pragma unroll
    for (int w = 0; w < 16; w++) { sg += s_redf[w]; cg2 += s_redi[w]; }
    float lc = s_ctot + sg + ((k > 0) ? (float)(k - cg2) * T : 0.0f);
    // post partials (device-scope atomics; visible cross-XCD), then flag
    atomicExch(&res[b * 4 + 0], __float_as_uint(s_ltot));
    atomicExch(&res[b * 4 + 1], __float_as_uint(lc));
    atomicExch(&res[b * 4 + 2], (unsigned)s_np);
    __threadfence();
    atomicExch(&res[b * 4 + 3], MAGIC);
  }

  // block 0, wave 0: gather all 128 partials and finalize (no extra kernel)
  if (b == 0 && tid < 64) {
    float ll = 0.0f, lc = 0.0f; int np = 0;
    #pragma unroll
    for (int h = 0; h < 2; h++) {
      const int i = tid + 64 * h;
      while (atomicAdd(&res[i * 4 + 3], 0u) != MAGIC) { __builtin_amdgcn_s_sleep(8); }
      ll += __uint_as_float(atomicAdd(&res[i * 4 + 0], 0u));
      lc += __uint_as_float(atomicAdd(&res[i * 4 + 1], 0u));
      np += (int)atomicAdd(&res[i * 4 + 2], 0u);
    }
    #pragma unroll
    for (int off = 32; off; off >>= 1) {
      ll += __shfl_down(ll, off);
      lc += __shfl_down(lc, off);
      np += __shfl_down(np, off);
    }
    if (tid == 0) {
      float fN = (float)np;
      out[0] = ll / fN;
      out[1] = lc / fN;
    }
  }
}

extern "C" void kernel_launch(void* const* d_in, const int* in_sizes, int n_in,
                              void* d_out, int out_size, void* d_ws, size_t ws_size,
                              hipStream_t stream) {
  const float* loc_data  = (const float*)d_in[0];
  const float* conf_data = (const float*)d_in[1];
  const float* dbox      = (const float*)d_in[2];
  const float* targets   = (const float*)d_in[3];
  float* out = (float*)d_out;

  char* ws = (char*)d_ws;
  float* ce0 = (float*)ws;                                           // B*P f32
  unsigned char* pack = (unsigned char*)(ws + (size_t)Bn * Pn * 4);  // B*P bytes
  unsigned long long* keys =
      (unsigned long long*)(ws + (size_t)Bn * Pn * 5);               // B*16 u64
  unsigned int* part =
      (unsigned int*)(ws + (size_t)Bn * Pn * 5 + (size_t)Bn * On * 8); // B*4 u32
  unsigned int* res = part + Bn * 4;                                 // B*4 u32

  // zero only the per-image partial accumulators (2 KB); keys/res are
  // poison-robust (atomicMax key encoding / atomicExch+MAGIC).
  hipMemsetAsync(part, 0, (size_t)Bn * 4 * sizeof(unsigned), stream);

  stream_kernel<<<1024, 256, 0, stream>>>(loc_data, conf_data, dbox, targets,
                                          ce0, pack, keys, part);
  reduce_kernel<<<Bn, 1024, 0, stream>>>(loc_data, conf_data, dbox, targets,
                                         ce0, pack, keys, part, res, out);
}

// Round 9
// 202.285 us; speedup vs baseline: 2.1563x; 1.0396x over previous
//
#include <hip/hip_runtime.h>
#include <cstddef>

#define Bn 128
#define Pn 8732
#define Cn 21
#define On 16
#define MAGIC 0x13579BDFu

__device__ __forceinline__ void argmax_combine(float& v, int& p, float v2, int p2) {
  if (v2 > v || (v2 == v && p2 < p)) { v = v2; p = p2; }
}

__device__ __forceinline__ float sl1_enc(float4 lv, float4 d,
                                         float t0, float t1, float t2, float t3) {
  float g0 = ((t0 + t2) * 0.5f - d.x) / (0.1f * d.z);
  float g1 = ((t1 + t3) * 0.5f - d.y) / (0.1f * d.w);
  float g2 = __logf((t2 - t0) / d.z) / 0.2f;
  float g3 = __logf((t3 - t1) / d.w) / 0.2f;
  float r = 0.f, a;
  a = fabsf(lv.x - g0); r += (a < 1.f) ? 0.5f * a * a : a - 0.5f;
  a = fabsf(lv.y - g1); r += (a < 1.f) ? 0.5f * a * a : a - 0.5f;
  a = fabsf(lv.z - g2); r += (a < 1.f) ? 0.5f * a * a : a - 0.5f;
  a = fabsf(lv.w - g3); r += (a < 1.f) ? 0.5f * a * a : a - 0.5f;
  return r;
}

// ---------------------------------------------------------------------------
// Kernel A: EXACT round-2 structure (measured 62 us; best of all variants).
// 4096 waves = 128 images x 32 chunk-groups, 5 chunks each, per-wave LDS
// staging, fast transcendentals. No pos-work here (round-8 lesson: any
// per-prior addition to this latency-bound phase costs ~16 us).
// ---------------------------------------------------------------------------
__global__ __launch_bounds__(256) void stream_kernel(
    const float* __restrict__ conf, const float* __restrict__ dbox,
    const float* __restrict__ targets,
    float* __restrict__ ce0, unsigned char* __restrict__ pack,
    unsigned long long* __restrict__ keys) {
  const int wb = threadIdx.x >> 6, lane = threadIdx.x & 63;
  const int wave_g = blockIdx.x * 4 + wb;
  const int b = wave_g & 127;
  const int cg = wave_g >> 7;                    // 0..31

  __shared__ float4 s_row4[4][336];              // 5376 B per wave
  __shared__ float s_tt[4][On * 5];
  __shared__ float s_ar[4][On];

  // On*5 = 80 > 64 lanes: strided fill covers elements 64..79 (truths 12-15).
  for (int i = lane; i < On * 5; i += 64)
    s_tt[wb][i] = targets[(size_t)b * On * 5 + i];
  if (lane < On) {
    float x1 = targets[(size_t)b * On * 5 + lane * 5 + 0];
    float y1 = targets[(size_t)b * On * 5 + lane * 5 + 1];
    float x2 = targets[(size_t)b * On * 5 + lane * 5 + 2];
    float y2 = targets[(size_t)b * On * 5 + lane * 5 + 3];
    s_ar[wb][lane] = (x2 - x1) * (y2 - y1);
  }

  float bestv[On]; int bestp[On];
  #pragma unroll
  for (int j = 0; j < On; j++) { bestv[j] = -1.0f; bestp[j] = 0x7fffffff; }

  #pragma unroll
  for (int i = 0; i < 5; i++) {
    const int ci = cg + 32 * i;
    if (ci >= 137) break;
    const int p0 = ci * 64;
    const int rows = min(64, Pn - p0);           // 64 or 28 (both %4==0)
    const int n4 = rows * Cn / 4;                // 336 or 147

    const float4* src = (const float4*)(conf + ((size_t)b * Pn + p0) * Cn);
    float4 v0, v1, v2, v3, v4, v5;
    if (lane < n4)        v0 = src[lane];
    if (lane + 64 < n4)   v1 = src[lane + 64];
    if (lane + 128 < n4)  v2 = src[lane + 128];
    if (lane + 192 < n4)  v3 = src[lane + 192];
    if (lane + 256 < n4)  v4 = src[lane + 256];
    if (lane + 320 < n4)  v5 = src[lane + 320];
    if (lane < n4)        s_row4[wb][lane] = v0;
    if (lane + 64 < n4)   s_row4[wb][lane + 64] = v1;
    if (lane + 128 < n4)  s_row4[wb][lane + 128] = v2;
    if (lane + 192 < n4)  s_row4[wb][lane + 192] = v3;
    if (lane + 256 < n4)  s_row4[wb][lane + 256] = v4;
    if (lane + 320 < n4)  s_row4[wb][lane + 320] = v5;

    if (lane < rows) {
      const int p = p0 + lane;
      const float* x = (const float*)s_row4[wb] + lane * Cn;  // stride 21: 2-way, free
      float m = x[0];
      #pragma unroll
      for (int q = 1; q < Cn; q++) m = fmaxf(m, x[q]);
      float s = 0.0f;
      #pragma unroll
      for (int q = 0; q < Cn; q++) s += __expf(x[q] - m);
      float lse = m + __logf(s);
      ce0[(size_t)b * Pn + p] = lse - x[0];

      float4 d = ((const float4*)dbox)[p];
      float px1 = d.x - d.z * 0.5f, py1 = d.y - d.w * 0.5f;
      float px2 = d.x + d.z * 0.5f, py2 = d.y + d.w * 0.5f;
      float ap = d.z * d.w;
      float mv = -1.0f; int mj = 0;
      #pragma unroll
      for (int j = 0; j < On; j++) {
        float lx = fmaxf(s_tt[wb][j*5+0], px1);
        float ly = fmaxf(s_tt[wb][j*5+1], py1);
        float rx = fminf(s_tt[wb][j*5+2], px2);
        float ry = fminf(s_tt[wb][j*5+3], py2);
        float w = fmaxf(rx - lx, 0.0f), h = fmaxf(ry - ly, 0.0f);
        float inter = w * h;
        float ov = __fdividef(inter, s_ar[wb][j] + ap - inter);
        if (ov > bestv[j]) { bestv[j] = ov; bestp[j] = p; }  // smallest p kept
        if (ov > mv) { mv = ov; mj = j; }                    // first max over j
      }
      pack[(size_t)b * Pn + p] =
          (unsigned char)(mj | ((mv >= 0.5f) ? 16 : 0));
    }
  }

  // per-truth argmax: wave shuffle reduce, then device atomicMax
  #pragma unroll
  for (int j = 0; j < On; j++) {
    float v = bestv[j]; int p = bestp[j];
    #pragma unroll
    for (int off = 32; off; off >>= 1) {
      float v2 = __shfl_down(v, off);
      int p2 = __shfl_down(p, off);
      argmax_combine(v, p, v2, p2);
    }
    if (lane == 0) {
      unsigned long long key;
      if (v < 0.0f) key = 0xC000000000000000ull;   // neutral, still beats poison
      else key = (((unsigned long long)(__float_as_uint(v) | 0xC0000000u)) << 32)
               | (unsigned long long)(0xFFFFFFFFu - (unsigned)p);
      atomicMax(&keys[b * On + j], key);
    }
  }
}

// ---------------------------------------------------------------------------
// Kernel B: round-2 reduce with one change: forced-match handling via LDS
// BITMAP (273 u32) instead of 16 compares x 9 elements per thread. Bulk pass
// skips forced priors' losses; wave 0 computes the <=16 forced losses
// directly (full add -- nothing to cancel). Radix top-k + MAGIC finalize
// unchanged.
// ---------------------------------------------------------------------------
__global__ __launch_bounds__(1024) void reduce_kernel(
    const float* __restrict__ loc, const float* __restrict__ conf,
    const float* __restrict__ dbox, const float* __restrict__ targets,
    const float* __restrict__ ce0, const unsigned char* __restrict__ pack,
    const unsigned long long* __restrict__ keys,
    unsigned int* __restrict__ res, float* __restrict__ out) {
  const int b = blockIdx.x;
  const int tid = threadIdx.x;
  const int wave = tid >> 6, lane = tid & 63;

  __shared__ float s_t[On * 5];
  __shared__ int s_bp[On];
  __shared__ unsigned s_bm[273];            // prior bitmap: 273*32 >= 8732
  __shared__ unsigned hist[256 * 16];       // [bin][wave], 16 KB
  __shared__ unsigned s_col[256];
  __shared__ unsigned s_cand[64];
  __shared__ float s_redf[2][16];
  __shared__ int s_redi[16];
  __shared__ unsigned s_prefix;
  __shared__ int s_kk;
  __shared__ int s_cnt;
  __shared__ int s_cc;
  __shared__ int s_np;
  __shared__ float s_floc, s_fcep;

  if (tid < On * 5) s_t[tid] = targets[(size_t)b * On * 5 + tid];
  if (tid < 273) s_bm[tid] = 0;
  __syncthreads();
  if (tid < On) {
    int bp = (int)(0xFFFFFFFFu - (unsigned)(keys[b * On + tid] & 0xFFFFFFFFull));
    s_bp[tid] = bp;
    atomicOr(&s_bm[bp >> 5], 1u << (bp & 31));
  }
  __syncthreads();

  // ---- wave 0, lanes 0-15: losses for the <=16 forced priors ----
  if (wave == 0) {
    float f_loc = 0.f, f_cep = 0.f;
    const bool valid = lane < On;
    const int p = valid ? s_bp[lane] : 0;
    bool dup = false;
    if (valid)
      for (int j2 = lane + 1; j2 < On; j2++) dup |= (s_bp[j2] == p);
    if (valid && !dup) {                     // last j wins on collisions
      const float* row = conf + ((size_t)b * Pn + p) * Cn;
      float m = row[0];
      #pragma unroll
      for (int q = 1; q < Cn; q++) m = fmaxf(m, row[q]);
      float s = 0.f;
      #pragma unroll
      for (int q = 0; q < Cn; q++) s += __expf(row[q] - m);
      const float lse = m + __logf(s);
      const int c = (int)s_t[lane * 5 + 4] + 1;
      f_cep = lse - row[c];                  // global read: no runtime reg-idx
      const float4 d = ((const float4*)dbox)[p];
      const float4 lv = ((const float4*)loc)[(size_t)b * Pn + p];
      f_loc = sl1_enc(lv, d, s_t[lane*5+0], s_t[lane*5+1],
                             s_t[lane*5+2], s_t[lane*5+3]);
    }
    #pragma unroll
    for (int off = 32; off; off >>= 1) {
      f_loc += __shfl_down(f_loc, off);
      f_cep += __shfl_down(f_cep, off);
    }
    if (lane == 0) { s_floc = f_loc; s_fcep = f_cep; }
  }

  // ---- bulk data pass (bitmap test instead of 16 compares) ----
  float ce_r[9];
  float my_loc = 0.0f, my_cep = 0.0f; int my_np = 0;
  #pragma unroll
  for (int sI = 0; sI < 9; sI++) {
    ce_r[sI] = 0.0f;
    const int p = tid + 1024 * sI;
    if (p < Pn) {
      unsigned char pk = pack[(size_t)b * Pn + p];
      float c0 = ce0[(size_t)b * Pn + p];
      const unsigned forced = (s_bm[p >> 5] >> (p & 31)) & 1u;
      const int posb = (pk >> 4);
      const int pos = posb | (int)forced;
      ce_r[sI] = pos ? 0.0f : c0;
      if (pos) my_np++;                      // forced counted once here
      if (posb && !forced) {                 // forced losses handled by wave 0
        const int bt = pk & 15;
        const float* t = &s_t[bt * 5];
        int c = (int)t[4] + 1;
        const float* row = conf + ((size_t)b * Pn + p) * Cn;
        my_cep += c0 + row[0] - row[c];      // lse - x[c]
        float4 d = ((const float4*)dbox)[p];
        float4 ld = ((const float4*)loc)[(size_t)b * Pn + p];
        my_loc += sl1_enc(ld, d, t[0], t[1], t[2], t[3]);
      }
    }
  }

  {
    int np = my_np;
    #pragma unroll
    for (int off = 32; off; off >>= 1) np += __shfl_down(np, off);
    if (lane == 0) s_redi[wave] = np;
  }
  __syncthreads();
  if (tid == 0) {
    int np = 0;
    #pragma unroll
    for (int w = 0; w < 16; w++) np += s_redi[w];
    s_np = np;
  }
  __syncthreads();

  // ---- exact k-th largest over register ce_neg values (all >= 0) ----
  const int k = min(s_np * 3, Pn);
  unsigned prefix = 0, maskb = 0;
  int kk = k;
  int cntc = Pn;
  for (int shift = 24; shift >= 0; shift -= 8) {
    if (cntc <= 64) break;                         // small-select path below
    ((uint4*)hist)[tid] = make_uint4(0u, 0u, 0u, 0u);
    __syncthreads();
    #pragma unroll
    for (int sI = 0; sI < 9; sI++) {
      const int p = tid + 1024 * sI;
      if (p < Pn) {
        unsigned u = __float_as_uint(ce_r[sI]);
        if ((u & maskb) == prefix)
          atomicAdd(&hist[(((u >> shift) & 255u) << 4) + (unsigned)wave], 1u);
      }
    }
    __syncthreads();
    if (tid < 256) {
      unsigned c = 0;
      #pragma unroll
      for (int w = 0; w < 16; w++) c += hist[(tid << 4) + w];
      s_col[tid] = c;
    }
    __syncthreads();
    if (tid < 64) {
      // wave-0 parallel suffix scan over 256 bins (4 per lane)
      unsigned c0 = s_col[4 * tid + 0], c1 = s_col[4 * tid + 1];
      unsigned c2 = s_col[4 * tid + 2], c3 = s_col[4 * tid + 3];
      unsigned t0 = c0 + c1 + c2 + c3;
      unsigned S = t0;
      #pragma unroll
      for (int off = 1; off < 64; off <<= 1) {
        unsigned o = __shfl_down(S, off);
        if (tid + off < 64) S += o;
      }
      unsigned Snext = S - t0;                     // suffix of lanes > tid
      unsigned s3 = Snext + c3;
      unsigned s2 = s3 + c2;
      unsigned s1 = s2 + c1;
      unsigned s0 = s1 + c0;
      unsigned kk_u = (unsigned)kk;
      int chosen = -1; unsigned snx = 0, cc = 0;
      if (s3 >= kk_u && Snext < kk_u)      { chosen = 3; snx = Snext; cc = c3; }
      else if (s2 >= kk_u && s3 < kk_u)    { chosen = 2; snx = s3;    cc = c2; }
      else if (s1 >= kk_u && s2 < kk_u)    { chosen = 1; snx = s2;    cc = c1; }
      else if (s0 >= kk_u && s1 < kk_u)    { chosen = 0; snx = s1;    cc = c0; }
      if (chosen >= 0) {                           // exactly one lane hits
        s_prefix = prefix | ((unsigned)(4 * tid + chosen) << shift);
        s_kk = (int)(kk_u - snx);
        s_cnt = (int)cc;
      }
    }
    __syncthreads();
    prefix = s_prefix; kk = s_kk; cntc = s_cnt;
    maskb |= 255u << shift;
  }
  if (maskb != 0xFFFFFFFFu) {
    // <= 64 candidates share the prefix: exact rank-select in one wave
    if (tid == 0) s_cc = 0;
    __syncthreads();
    #pragma unroll
    for (int sI = 0; sI < 9; sI++) {
      const int p = tid + 1024 * sI;
      if (p < Pn) {
        unsigned u = __float_as_uint(ce_r[sI]);
        if ((u & maskb) == prefix) {
          int ix = atomicAdd(&s_cc, 1);
          if (ix < 64) s_cand[ix] = u;
        }
      }
    }
    __syncthreads();
    if (tid < 64) {
      int c = min(s_cc, 64);
      if (tid < c) {
        unsigned v = s_cand[tid];
        int g = 0, e = 0;
        for (int i = 0; i < c; i++) {
          unsigned w = s_cand[i];
          g += (w > v); e += (w == v);
        }
        if (g < kk && kk <= g + e) s_prefix = v;   // tie-safe: all writers equal
      }
    }
    __syncthreads();
    prefix = s_prefix;
  }
  float T = __uint_as_float(prefix);

  float sum_gt = 0.0f; int cnt_gt = 0;
  #pragma unroll
  for (int sI = 0; sI < 9; sI++) {
    const int p = tid + 1024 * sI;
    if (p < Pn) {
      float x = ce_r[sI];
      if (x > T) { sum_gt += x; cnt_gt++; }
    }
  }
  #pragma unroll
  for (int off = 32; off; off >>= 1) {
    sum_gt += __shfl_down(sum_gt, off);
    cnt_gt += __shfl_down(cnt_gt, off);
    my_loc += __shfl_down(my_loc, off);
    my_cep += __shfl_down(my_cep, off);
  }
  if (lane == 0) {
    s_redf[0][wave] = my_loc; s_redf[1][wave] = sum_gt + my_cep; s_redi[wave] = cnt_gt;
  }
  __syncthreads();
  if (tid == 0) {
    float ll = s_floc, lc = s_fcep; int cg2 = 0;
    #pragma unroll
    for (int w = 0; w < 16; w++) {
      ll += s_redf[0][w]; lc += s_redf[1][w]; cg2 += s_redi[w];
    }
    lc += (k > 0) ? (float)(k - cg2) * T : 0.0f;
    // post partials (device-scope atomics; visible cross-XCD), then flag
    atomicExch(&res[b * 4 + 0], __float_as_uint(ll));
    atomicExch(&res[b * 4 + 1], __float_as_uint(lc));
    atomicExch(&res[b * 4 + 2], (unsigned)s_np);
    __threadfence();
    atomicExch(&res[b * 4 + 3], MAGIC);
  }

  // block 0, wave 0: gather all 128 partials and finalize (no extra kernel)
  if (b == 0 && tid < 64) {
    float ll = 0.0f, lc = 0.0f; int np = 0;
    #pragma unroll
    for (int h = 0; h < 2; h++) {
      const int i = tid + 64 * h;
      while (atomicAdd(&res[i * 4 + 3], 0u) != MAGIC) { __builtin_amdgcn_s_sleep(8); }
      ll += __uint_as_float(atomicAdd(&res[i * 4 + 0], 0u));
      lc += __uint_as_float(atomicAdd(&res[i * 4 + 1], 0u));
      np += (int)atomicAdd(&res[i * 4 + 2], 0u);
    }
    #pragma unroll
    for (int off = 32; off; off >>= 1) {
      ll += __shfl_down(ll, off);
      lc += __shfl_down(lc, off);
      np += __shfl_down(np, off);
    }
    if (tid == 0) {
      float fN = (float)np;
      out[0] = ll / fN;
      out[1] = lc / fN;
    }
  }
}

extern "C" void kernel_launch(void* const* d_in, const int* in_sizes, int n_in,
                              void* d_out, int out_size, void* d_ws, size_t ws_size,
                              hipStream_t stream) {
  const float* loc_data  = (const float*)d_in[0];
  const float* conf_data = (const float*)d_in[1];
  const float* dbox      = (const float*)d_in[2];
  const float* targets   = (const float*)d_in[3];
  float* out = (float*)d_out;

  char* ws = (char*)d_ws;
  float* ce0 = (float*)ws;                                           // B*P f32
  unsigned char* pack = (unsigned char*)(ws + (size_t)Bn * Pn * 4);  // B*P bytes
  unsigned long long* keys =
      (unsigned long long*)(ws + (size_t)Bn * Pn * 5);               // B*16 u64
  unsigned int* res = (unsigned int*)(ws + (size_t)Bn * Pn * 5 + Bn * On * 8); // B*4 u32

  stream_kernel<<<1024, 256, 0, stream>>>(conf_data, dbox, targets, ce0, pack, keys);
  reduce_kernel<<<Bn, 1024, 0, stream>>>(loc_data, conf_data, dbox, targets,
                                         ce0, pack, keys, res, out);
}